// Round 1
// baseline (1269.797 us; speedup 1.0000x reference)
//
#include <hip/hip_runtime.h>

#define BATCH 64
#define CIN 256
#define C2 128
#define NPIX 1600
#define SDIM 725
#define SPAD 728
#define NTB 25   // n tiles of 64 (1600/64)
#define STB 12   // s tiles of 64 (ceil(725/64))
#define NBLK 25  // partial stat blocks per (b,s)

// ---------------- K1: conv1x1 for g and theta branches ----------------
// out[b][o][n] = sum_c W[o][c] * x[b][c][n] + bias[o],  o<128, n<1600, c<256
__global__ __launch_bounds__(256) void k1_conv(
    const float* __restrict__ x,
    const float* __restrict__ gw, const float* __restrict__ gb,
    const float* __restrict__ tw, const float* __restrict__ tb,
    float* __restrict__ gout, float* __restrict__ tout)
{
    int blk = blockIdx.x;
    int nt = blk % NTB; blk /= NTB;
    int ot = blk & 1; blk >>= 1;
    int mat = blk & 1; blk >>= 1;
    int b = blk;
    const float* W  = mat ? tw : gw;
    const float* bi = mat ? tb : gb;
    float* out      = mat ? tout : gout;
    const float* xb = x + (size_t)b * CIN * NPIX;
    int o0 = ot * 64, n0 = nt * 64;

    __shared__ float As[32][68];
    __shared__ float Bs[32][68];
    int tid = threadIdx.x;
    int tm = tid >> 4, tn = tid & 15;
    float acc[4][4] = {};

    for (int k0 = 0; k0 < CIN; k0 += 32) {
        int kkA = tid & 31, mmb = tid >> 5;
        #pragma unroll
        for (int p = 0; p < 8; ++p)
            As[kkA][mmb + 8 * p] = W[(size_t)(o0 + mmb + 8 * p) * CIN + k0 + kkA];
        int q4 = (tid & 15) * 4, kb = tid >> 4;
        #pragma unroll
        for (int p = 0; p < 2; ++p) {
            float4 v = *reinterpret_cast<const float4*>(
                &xb[(size_t)(k0 + kb + 16 * p) * NPIX + n0 + q4]);
            *reinterpret_cast<float4*>(&Bs[kb + 16 * p][q4]) = v;
        }
        __syncthreads();
        #pragma unroll
        for (int kk = 0; kk < 32; ++kk) {
            float4 a4 = *reinterpret_cast<const float4*>(&As[kk][tm * 4]);
            float4 b4 = *reinterpret_cast<const float4*>(&Bs[kk][tn * 4]);
            float av[4] = {a4.x, a4.y, a4.z, a4.w};
            float bv[4] = {b4.x, b4.y, b4.z, b4.w};
            #pragma unroll
            for (int i = 0; i < 4; ++i)
                #pragma unroll
                for (int j = 0; j < 4; ++j)
                    acc[i][j] += av[i] * bv[j];
        }
        __syncthreads();
    }
    #pragma unroll
    for (int i = 0; i < 4; ++i) {
        int o = o0 + tm * 4 + i;
        float bs = bi[o];
        float4 r = make_float4(acc[i][0] + bs, acc[i][1] + bs,
                               acc[i][2] + bs, acc[i][3] + bs);
        *reinterpret_cast<float4*>(&out[((size_t)b * C2 + o) * NPIX + n0 + tn * 4]) = r;
    }
}

// ---------------- K2: PSP multi-scale pooling (faithful raw-reshape) ----------------
// phi[bc][j] padded to SPAD=728 (pad columns = 0)
__global__ void k2_psp(const float* __restrict__ g, float* __restrict__ phi)
{
    int idx = blockIdx.x * 256 + threadIdx.x;
    if (idx >= BATCH * C2 * SPAD) return;
    int j = idx % SPAD;
    int bc = idx / SPAD;
    float outv = 0.f;
    if (j < SDIM) {
        int ls, off;
        if (j < 25)       { ls = 0; off = 0; }
        else if (j < 125) { ls = 2; off = 25; }
        else if (j < 325) { ls = 3; off = 125; }
        else              { ls = 4; off = 325; }
        int m = j - off;
        int flat = (bc << ls) * 25 + m;          // bc*s*25 + m
        int a   = flat >> (7 + ls);              // / (128*s)
        int rem = flat & ((128 << ls) - 1);
        int c2  = rem >> ls;
        int k   = rem & ((1 << ls) - 1);
        int L   = 64 >> ls;                      // t/s
        const float* p = g + ((size_t)a << 13) + (c2 << 6) + k * L;
        float sum = 0.f;
        for (int q = 0; q < L; q += 4) {
            float4 v = *reinterpret_cast<const float4*>(p + q);
            sum += v.x + v.y + v.z + v.w;
        }
        outv = sum * (1.f / L);
    }
    phi[idx] = outv;
}

// ---------------- K3: f = theta^T * phi tile + per-column (over n) softmax partials ----------------
__global__ __launch_bounds__(256) void k3_gemm1_stats(
    const float* __restrict__ theta, const float* __restrict__ phi,
    float* __restrict__ pmax, float* __restrict__ psum)
{
    int blk = blockIdx.x;
    int st = blk % STB; blk /= STB;
    int nt = blk % NTB; int b = blk / NTB;
    int n0 = nt * 64, s0 = st * 64;
    const float* A = theta + (size_t)b * C2 * NPIX;
    const float* P = phi + (size_t)b * C2 * SPAD;

    __shared__ float As[32][68];
    __shared__ float Bs[32][68];
    __shared__ float red[64][17];
    __shared__ float cm[64];

    int tid = threadIdx.x;
    int tm = tid >> 4, tn = tid & 15;
    float acc[4][4] = {};

    for (int k0 = 0; k0 < C2; k0 += 32) {
        int q4 = (tid & 15) * 4, kb = tid >> 4;
        #pragma unroll
        for (int p = 0; p < 2; ++p) {
            int kk = kb + 16 * p;
            *reinterpret_cast<float4*>(&As[kk][q4]) =
                *reinterpret_cast<const float4*>(&A[(size_t)(k0 + kk) * NPIX + n0 + q4]);
            float4 bv = make_float4(0.f, 0.f, 0.f, 0.f);
            if (s0 + q4 < SPAD)
                bv = *reinterpret_cast<const float4*>(&P[(size_t)(k0 + kk) * SPAD + s0 + q4]);
            *reinterpret_cast<float4*>(&Bs[kk][q4]) = bv;
        }
        __syncthreads();
        #pragma unroll
        for (int kk = 0; kk < 32; ++kk) {
            float4 a4 = *reinterpret_cast<const float4*>(&As[kk][tm * 4]);
            float4 b4 = *reinterpret_cast<const float4*>(&Bs[kk][tn * 4]);
            float av[4] = {a4.x, a4.y, a4.z, a4.w};
            float bv[4] = {b4.x, b4.y, b4.z, b4.w};
            #pragma unroll
            for (int i = 0; i < 4; ++i)
                #pragma unroll
                for (int j = 0; j < 4; ++j)
                    acc[i][j] += av[i] * bv[j];
        }
        __syncthreads();
    }
    // per-column (s) max over the 64 n's of this tile
    #pragma unroll
    for (int j = 0; j < 4; ++j) {
        float lm = fmaxf(fmaxf(acc[0][j], acc[1][j]), fmaxf(acc[2][j], acc[3][j]));
        red[tn * 4 + j][tm] = lm;
    }
    __syncthreads();
    if (tid < 64) {
        float m = red[tid][0];
        #pragma unroll
        for (int k = 1; k < 16; ++k) m = fmaxf(m, red[tid][k]);
        cm[tid] = m;
    }
    __syncthreads();
    #pragma unroll
    for (int j = 0; j < 4; ++j) {
        float m = cm[tn * 4 + j];
        float ls = __expf(acc[0][j] - m) + __expf(acc[1][j] - m) +
                   __expf(acc[2][j] - m) + __expf(acc[3][j] - m);
        red[tn * 4 + j][tm] = ls;
    }
    __syncthreads();
    if (tid < 64) {
        float z = 0.f;
        #pragma unroll
        for (int k = 0; k < 16; ++k) z += red[tid][k];
        int s = s0 + tid;
        if (s < SDIM) {
            pmax[((size_t)b * SDIM + s) * NBLK + nt] = cm[tid];
            psum[((size_t)b * SDIM + s) * NBLK + nt] = z;
        }
    }
}

// ---------------- K4: combine per-block partials -> column m, Z ----------------
__global__ void k4_combine(const float* __restrict__ pmax, const float* __restrict__ psum,
                           float* __restrict__ colm, float* __restrict__ colz)
{
    int idx = blockIdx.x * 256 + threadIdx.x;
    if (idx >= BATCH * SDIM) return;
    const float* pm = pmax + (size_t)idx * NBLK;
    const float* pz = psum + (size_t)idx * NBLK;
    float m = -1e30f;
    for (int i = 0; i < NBLK; ++i) m = fmaxf(m, pm[i]);
    float z = 0.f;
    for (int i = 0; i < NBLK; ++i) z += pz[i] * __expf(pm[i] - m);
    colm[idx] = m;
    colz[idx] = z;
}

// ---------------- K5: recompute f tile, normalize, y = softmax(f) @ phi^T ----------------
__global__ __launch_bounds__(256) void k5_attn(
    const float* __restrict__ theta, const float* __restrict__ phi,
    const float* __restrict__ colm, const float* __restrict__ colz,
    float* __restrict__ y)
{
    int nt = blockIdx.x % NTB, b = blockIdx.x / NTB;
    int n0 = nt * 64;
    const float* Tb = theta + (size_t)b * C2 * NPIX;
    const float* Pb = phi + (size_t)b * C2 * SPAD;

    __shared__ float th[C2][68];
    __shared__ float ph[C2][36];
    __shared__ float pt[64][33];
    __shared__ float sm_m[SPAD];
    __shared__ float sm_zi[SPAD];

    int tid = threadIdx.x;
    {
        int q4 = (tid & 15) * 4, cb = tid >> 4;
        #pragma unroll
        for (int p = 0; p < 8; ++p) {
            int c = cb + 16 * p;
            *reinterpret_cast<float4*>(&th[c][q4]) =
                *reinterpret_cast<const float4*>(&Tb[(size_t)c * NPIX + n0 + q4]);
        }
        for (int i = tid; i < SDIM; i += 256) {
            sm_m[i]  = colm[(size_t)b * SDIM + i];
            sm_zi[i] = 1.f / colz[(size_t)b * SDIM + i];
        }
    }
    __syncthreads();

    int tm1 = tid >> 3, tn1 = tid & 7;   // phase1: n = i*32+tm1 (i<2), s = tn1*4+j
    int tg = tid & 7, cg = tid >> 3;     // phase2: n = i*8+tg (i<8), c = cg+32*j
    float yacc[8][4] = {};

    for (int ch = 0; ch < 23; ++ch) {
        int sc0 = ch * 32;
        {
            int sl4 = (tid & 7) * 4, cr = tid >> 3;
            #pragma unroll
            for (int p = 0; p < 4; ++p) {
                int c = cr + 32 * p;
                float4 v = make_float4(0.f, 0.f, 0.f, 0.f);
                if (sc0 + sl4 < SPAD)
                    v = *reinterpret_cast<const float4*>(&Pb[(size_t)c * SPAD + sc0 + sl4]);
                *reinterpret_cast<float4*>(&ph[c][sl4]) = v;
            }
        }
        __syncthreads();
        // phase 1: f tile (64n x 32s) + normalize to p
        {
            float facc[2][4] = {};
            for (int c = 0; c < C2; ++c) {
                float a0 = th[c][tm1];
                float a1 = th[c][tm1 + 32];
                float4 b4 = *reinterpret_cast<const float4*>(&ph[c][tn1 * 4]);
                float bv[4] = {b4.x, b4.y, b4.z, b4.w};
                #pragma unroll
                for (int j = 0; j < 4; ++j) {
                    facc[0][j] += a0 * bv[j];
                    facc[1][j] += a1 * bv[j];
                }
            }
            #pragma unroll
            for (int i = 0; i < 2; ++i)
                #pragma unroll
                for (int j = 0; j < 4; ++j) {
                    int s = sc0 + tn1 * 4 + j;
                    float p = 0.f;
                    if (s < SDIM)
                        p = __expf(facc[i][j] - sm_m[s]) * sm_zi[s];
                    pt[i * 32 + tm1][tn1 * 4 + j] = p;
                }
        }
        __syncthreads();
        // phase 2: yacc[n][c] += p[n][ss] * phi[c][ss]
        for (int ss = 0; ss < 32; ++ss) {
            float pv[8];
            #pragma unroll
            for (int i = 0; i < 8; ++i) pv[i] = pt[i * 8 + tg][ss];
            #pragma unroll
            for (int j = 0; j < 4; ++j) {
                float bv = ph[cg + 32 * j][ss];
                #pragma unroll
                for (int i = 0; i < 8; ++i) yacc[i][j] += pv[i] * bv;
            }
        }
        __syncthreads();
    }
    #pragma unroll
    for (int i = 0; i < 8; ++i) {
        int n = n0 + i * 8 + tg;
        #pragma unroll
        for (int j = 0; j < 4; ++j)
            y[((size_t)b * NPIX + n) * C2 + cg + 32 * j] = yacc[i][j];
    }
}

// ---------------- K6: partial online (m,z) over n for y columns ----------------
__global__ void k6_ypart(const float* __restrict__ y, float* __restrict__ pm, float* __restrict__ pz)
{
    int b = blockIdx.x >> 4, ncch = blockIdx.x & 15;
    int c = threadIdx.x; // 128 threads
    const float* yb = y + ((size_t)b * NPIX + ncch * 100) * C2 + c;
    float m = -1e30f, z = 0.f;
    for (int r = 0; r < 100; ++r) {
        float v = yb[(size_t)r * C2];
        float nm = fmaxf(m, v);
        z = z * __expf(m - nm) + __expf(v - nm);
        m = nm;
    }
    pm[((size_t)b * C2 + c) * 16 + ncch] = m;
    pz[((size_t)b * C2 + c) * 16 + ncch] = z;
}

__global__ void k6b_ycomb(const float* __restrict__ pm, const float* __restrict__ pz,
                          float* __restrict__ ym, float* __restrict__ yzi)
{
    int idx = blockIdx.x * 256 + threadIdx.x;
    if (idx >= BATCH * C2) return;
    const float* m16 = pm + (size_t)idx * 16;
    const float* z16 = pz + (size_t)idx * 16;
    float m = -1e30f;
    for (int i = 0; i < 16; ++i) m = fmaxf(m, m16[i]);
    float z = 0.f;
    for (int i = 0; i < 16; ++i) z += z16[i] * __expf(m16[i] - m);
    ym[idx] = m;
    yzi[idx] = 1.f / z;
}

// ---------------- K7: final conv + residual + BN + ReLU ----------------
__global__ __launch_bounds__(256) void k7_final(
    const float* __restrict__ y, const float* __restrict__ ym, const float* __restrict__ yzi,
    const float* __restrict__ Ww, const float* __restrict__ Wb,
    const float* __restrict__ x,
    const float* __restrict__ gamma, const float* __restrict__ beta,
    const float* __restrict__ mean, const float* __restrict__ var,
    float* __restrict__ out)
{
    int blk = blockIdx.x;
    int nt = blk % NTB; blk /= NTB;
    int ot = blk & 3; int b = blk >> 2;
    int o0 = ot * 64, n0 = nt * 64;

    __shared__ float As[32][68];
    __shared__ float Bs[32][68];
    __shared__ float ml[C2], zl[C2];

    int tid = threadIdx.x;
    if (tid < C2) {
        ml[tid] = ym[(size_t)b * C2 + tid];
        zl[tid] = yzi[(size_t)b * C2 + tid];
    }
    __syncthreads();

    int tm = tid >> 4, tn = tid & 15;
    float acc[4][4] = {};
    for (int k0 = 0; k0 < C2; k0 += 32) {
        int kk = tid & 31, rb = tid >> 5;
        #pragma unroll
        for (int p = 0; p < 8; ++p)
            As[kk][rb + 8 * p] = Ww[(size_t)(o0 + rb + 8 * p) * C2 + k0 + kk];
        #pragma unroll
        for (int p = 0; p < 8; ++p) {
            int nn = rb + 8 * p;
            float v = y[((size_t)b * NPIX + n0 + nn) * C2 + k0 + kk];
            Bs[kk][nn] = __expf(v - ml[k0 + kk]) * zl[k0 + kk];
        }
        __syncthreads();
        #pragma unroll
        for (int kki = 0; kki < 32; ++kki) {
            float4 a4 = *reinterpret_cast<const float4*>(&As[kki][tm * 4]);
            float4 b4 = *reinterpret_cast<const float4*>(&Bs[kki][tn * 4]);
            float av[4] = {a4.x, a4.y, a4.z, a4.w};
            float bv[4] = {b4.x, b4.y, b4.z, b4.w};
            #pragma unroll
            for (int i = 0; i < 4; ++i)
                #pragma unroll
                for (int j = 0; j < 4; ++j)
                    acc[i][j] += av[i] * bv[j];
        }
        __syncthreads();
    }
    #pragma unroll
    for (int i = 0; i < 4; ++i) {
        int o = o0 + tm * 4 + i;
        float sc = gamma[o] * rsqrtf(var[o] + 1e-5f);
        float sh = beta[o] - mean[o] * sc;
        float wb = Wb[o];
        size_t base = ((size_t)b * CIN + o) * NPIX + n0 + tn * 4;
        float4 xr = *reinterpret_cast<const float4*>(&x[base]);
        float4 r;
        r.x = fmaxf((acc[i][0] + wb + xr.x) * sc + sh, 0.f);
        r.y = fmaxf((acc[i][1] + wb + xr.y) * sc + sh, 0.f);
        r.z = fmaxf((acc[i][2] + wb + xr.z) * sc + sh, 0.f);
        r.w = fmaxf((acc[i][3] + wb + xr.w) * sc + sh, 0.f);
        *reinterpret_cast<float4*>(&out[base]) = r;
    }
}

extern "C" void kernel_launch(void* const* d_in, const int* in_sizes, int n_in,
                              void* d_out, int out_size, void* d_ws, size_t ws_size,
                              hipStream_t stream)
{
    const float* x   = (const float*)d_in[0];
    const float* gw  = (const float*)d_in[1];
    const float* gb  = (const float*)d_in[2];
    const float* tw  = (const float*)d_in[3];
    const float* tb  = (const float*)d_in[4];
    const float* Ww  = (const float*)d_in[5];
    const float* Wb  = (const float*)d_in[6];
    const float* bng = (const float*)d_in[7];
    const float* bnb = (const float*)d_in[8];
    const float* bnm = (const float*)d_in[9];
    const float* bnv = (const float*)d_in[10];
    float* out = (float*)d_out;
    float* ws  = (float*)d_ws;

    // workspace layout (float offsets); y aliases gcv (dead after K2)
    float* theta = ws;                    // 13,107,200
    float* gcv   = ws + 13107200;         // 13,107,200 (later reused as y)
    float* phi   = ws + 26214400;         // 64*128*728 = 5,963,776
    float* pmax  = ws + 32178176;         // 1,160,000
    float* psum  = ws + 33338176;         // 1,160,000
    float* colm  = ws + 34498176;         // 46,400
    float* colz  = ws + 34544576;         // 46,400
    float* ypm   = ws + 34590976;         // 131,072
    float* ypz   = ws + 34722048;         // 131,072
    float* ymv   = ws + 34853120;         // 8,192
    float* yzi   = ws + 34861312;         // 8,192
    float* yv    = gcv;

    k1_conv<<<BATCH * 2 * 2 * NTB, 256, 0, stream>>>(x, gw, gb, tw, tb, gcv, theta);
    k2_psp<<<(BATCH * C2 * SPAD + 255) / 256, 256, 0, stream>>>(gcv, phi);
    k3_gemm1_stats<<<BATCH * NTB * STB, 256, 0, stream>>>(theta, phi, pmax, psum);
    k4_combine<<<(BATCH * SDIM + 255) / 256, 256, 0, stream>>>(pmax, psum, colm, colz);
    k5_attn<<<BATCH * NTB, 256, 0, stream>>>(theta, phi, colm, colz, yv);
    k6_ypart<<<BATCH * 16, 128, 0, stream>>>(yv, ypm, ypz);
    k6b_ycomb<<<(BATCH * C2 + 255) / 256, 256, 0, stream>>>(ypm, ypz, ymv, yzi);
    k7_final<<<BATCH * 4 * NTB, 256, 0, stream>>>(yv, ymv, yzi, Ww, Wb, x, bng, bnb, bnm, bnv, out);
}

// Round 2
// 680.191 us; speedup vs baseline: 1.8668x; 1.8668x over previous
//
#include <hip/hip_runtime.h>

#define NTB 25

typedef float f32x4 __attribute__((ext_vector_type(4)));
typedef short bf16x8 __attribute__((ext_vector_type(8)));

__device__ __forceinline__ ushort f2bf(float f) {
    union { float f; uint u; } v; v.f = f;
    uint u = v.u;
    return (ushort)((u + 0x7fffu + ((u >> 16) & 1u)) >> 16);
}
__device__ __forceinline__ float bf2f(ushort h) {
    union { uint u; float f; } v; v.u = ((uint)h) << 16;
    return v.f;
}

// ---------------- K1: fused conv1x1 (g & theta) via MFMA ----------------
// M=256 rows (gw 0..127, tw 128..255), N=64 pixels, K=256.
__global__ __launch_bounds__(256) void k1_conv(
    const float* __restrict__ x,
    const float* __restrict__ gw, const float* __restrict__ gb,
    const float* __restrict__ tw, const float* __restrict__ tb,
    ushort* __restrict__ gout, ushort* __restrict__ thT)
{
    int nt = blockIdx.x % NTB, b = blockIdx.x / NTB;
    int n0 = nt * 64;
    __shared__ ushort xl[8][64][40];   // 8 K-chunks, 64 n, 32 c (+swizzle pad)
    int tid = threadIdx.x, lane = tid & 63, w = tid >> 6;

    // stage x tile (bf16, transposed [n][c], XOR-swizzled 8-elem blocks)
    const float* xb = x + (size_t)b * 256 * 1600;
    int nr = tid & 15, cr = tid >> 4;
    for (int q = 0; q < 16; ++q) {
        int kc = q >> 1, p = q & 1;
        int c = cr + 16 * p;
        float4 v = *reinterpret_cast<const float4*>(
            &xb[(size_t)(kc * 32 + c) * 1600 + n0 + nr * 4]);
        float vv[4] = {v.x, v.y, v.z, v.w};
        #pragma unroll
        for (int j = 0; j < 4; ++j) {
            int n = nr * 4 + j;
            int blk = (c >> 3) ^ ((n >> 2) & 3);
            xl[kc][n][blk * 8 + (c & 7)] = f2bf(vv[j]);
        }
    }
    __syncthreads();

    const float* W    = (w < 2) ? gw : tw;
    const float* bias = (w < 2) ? gb : tb;
    int mrow0 = (w & 1) * 64;
    int lr = lane & 15, lg = lane >> 4;
    f32x4 acc[4][4] = {};

    #pragma unroll
    for (int kc = 0; kc < 8; ++kc) {
        bf16x8 af[4];
        #pragma unroll
        for (int mi = 0; mi < 4; ++mi) {
            const float* wp = &W[(size_t)(mrow0 + mi * 16 + lr) * 256 + kc * 32 + lg * 8];
            float4 w0 = *reinterpret_cast<const float4*>(wp);
            float4 w1 = *reinterpret_cast<const float4*>(wp + 4);
            bf16x8 a;
            a[0] = (short)f2bf(w0.x); a[1] = (short)f2bf(w0.y);
            a[2] = (short)f2bf(w0.z); a[3] = (short)f2bf(w0.w);
            a[4] = (short)f2bf(w1.x); a[5] = (short)f2bf(w1.y);
            a[6] = (short)f2bf(w1.z); a[7] = (short)f2bf(w1.w);
            af[mi] = a;
        }
        #pragma unroll
        for (int ni = 0; ni < 4; ++ni) {
            int n = ni * 16 + lr;
            int blk = lg ^ ((n >> 2) & 3);
            bf16x8 bfrag = *reinterpret_cast<const bf16x8*>(&xl[kc][n][blk * 8]);
            #pragma unroll
            for (int mi = 0; mi < 4; ++mi)
                acc[mi][ni] = __builtin_amdgcn_mfma_f32_16x16x32_bf16(
                    af[mi], bfrag, acc[mi][ni], 0, 0, 0);
        }
    }

    #pragma unroll
    for (int mi = 0; mi < 4; ++mi) {
        float4 bv = *reinterpret_cast<const float4*>(&bias[mrow0 + mi * 16 + lg * 4]);
        float bvv[4] = {bv.x, bv.y, bv.z, bv.w};
        #pragma unroll
        for (int ni = 0; ni < 4; ++ni) {
            int n = n0 + ni * 16 + lr;
            int m = mrow0 + mi * 16 + lg * 4;
            if (w < 2) {
                #pragma unroll
                for (int r = 0; r < 4; ++r)
                    gout[((size_t)b * 128 + m + r) * 1600 + n] = f2bf(acc[mi][ni][r] + bvv[r]);
            } else {
                ushort4 pk;
                pk.x = f2bf(acc[mi][ni][0] + bvv[0]);
                pk.y = f2bf(acc[mi][ni][1] + bvv[1]);
                pk.z = f2bf(acc[mi][ni][2] + bvv[2]);
                pk.w = f2bf(acc[mi][ni][3] + bvv[3]);
                *reinterpret_cast<ushort4*>(&thT[((size_t)b * 1600 + n) * 128 + m]) = pk;
            }
        }
    }
}

// ---------------- K2: PSP pooling (faithful raw reshape), both phi layouts ----------------
__global__ __launch_bounds__(256) void k2a_psp(const ushort* __restrict__ g,
                                               ushort* __restrict__ phiC,
                                               ushort* __restrict__ phiT)
{
    int idx = blockIdx.x * 256 + threadIdx.x;   // (b*128 + c)*768 + j
    if (idx >= 64 * 128 * 768) return;
    int j = idx % 768;
    int bc = idx / 768;
    float outv = 0.f;
    if (j < 725) {
        int ls, off;
        if (j < 25)       { ls = 0; off = 0; }
        else if (j < 125) { ls = 2; off = 25; }
        else if (j < 325) { ls = 3; off = 125; }
        else              { ls = 4; off = 325; }
        int m = j - off;
        int flat = (bc << ls) * 25 + m;
        int a   = flat >> (7 + ls);
        int rem = flat & ((128 << ls) - 1);
        int c2  = rem >> ls;
        int k   = rem & ((1 << ls) - 1);
        int L   = 64 >> ls;
        const ushort* p = g + ((size_t)a << 13) + (c2 << 6) + k * L;
        float sum = 0.f;
        for (int q = 0; q < L; ++q) sum += bf2f(p[q]);
        outv = sum * (1.f / L);
    }
    ushort hv = f2bf(outv);
    phiC[idx] = hv;
    int b = bc >> 7, c = bc & 127;
    phiT[((size_t)b * 768 + j) * 128 + c] = hv;
}

// ---------------- K3: f = theta^T phi (MFMA) + column softmax partials ----------------
__global__ __launch_bounds__(256) void k3_stats(
    const ushort* __restrict__ thT, const ushort* __restrict__ phiT,
    float* __restrict__ pmax, float* __restrict__ psum)
{
    int blk = blockIdx.x;
    int st = blk % 12; blk /= 12;
    int nt = blk % 25; int b = blk / 25;
    int n0 = nt * 64, s0 = st * 64;
    int tid = threadIdx.x, lane = tid & 63, w = tid >> 6;
    int lr = lane & 15, lg = lane >> 4;
    int nq = (w & 1) * 32, sq = (w >> 1) * 32;

    f32x4 acc[2][2] = {};
    #pragma unroll
    for (int kc = 0; kc < 4; ++kc) {
        bf16x8 a[2], bb[2];
        #pragma unroll
        for (int mi = 0; mi < 2; ++mi)
            a[mi] = *reinterpret_cast<const bf16x8*>(
                &thT[((size_t)b * 1600 + n0 + nq + mi * 16 + lr) * 128 + kc * 32 + lg * 8]);
        #pragma unroll
        for (int ni = 0; ni < 2; ++ni)
            bb[ni] = *reinterpret_cast<const bf16x8*>(
                &phiT[((size_t)b * 768 + s0 + sq + ni * 16 + lr) * 128 + kc * 32 + lg * 8]);
        #pragma unroll
        for (int mi = 0; mi < 2; ++mi)
            #pragma unroll
            for (int ni = 0; ni < 2; ++ni)
                acc[mi][ni] = __builtin_amdgcn_mfma_f32_16x16x32_bf16(
                    a[mi], bb[ni], acc[mi][ni], 0, 0, 0);
    }

    __shared__ float redm[64][2];
    __shared__ float cmx[64];
    __shared__ float reds[64][2];

    float mx[2];
    #pragma unroll
    for (int ni = 0; ni < 2; ++ni) {
        float m = acc[0][ni][0];
        #pragma unroll
        for (int r = 1; r < 4; ++r) m = fmaxf(m, acc[0][ni][r]);
        #pragma unroll
        for (int r = 0; r < 4; ++r) m = fmaxf(m, acc[1][ni][r]);
        m = fmaxf(m, __shfl_xor(m, 16));
        m = fmaxf(m, __shfl_xor(m, 32));
        mx[ni] = m;
    }
    if (lg == 0) {
        redm[sq + lr][w & 1] = mx[0];
        redm[sq + 16 + lr][w & 1] = mx[1];
    }
    __syncthreads();
    if (tid < 64) cmx[tid] = fmaxf(redm[tid][0], redm[tid][1]);
    __syncthreads();
    float se[2];
    #pragma unroll
    for (int ni = 0; ni < 2; ++ni) {
        float m = cmx[sq + ni * 16 + lr];
        float s = 0.f;
        #pragma unroll
        for (int r = 0; r < 4; ++r)
            s += __expf(acc[0][ni][r] - m) + __expf(acc[1][ni][r] - m);
        s += __shfl_xor(s, 16);
        s += __shfl_xor(s, 32);
        se[ni] = s;
    }
    if (lg == 0) {
        reds[sq + lr][w & 1] = se[0];
        reds[sq + 16 + lr][w & 1] = se[1];
    }
    __syncthreads();
    if (tid < 64) {
        int s = s0 + tid;
        pmax[((size_t)b * 768 + s) * 25 + nt] = cmx[tid];
        psum[((size_t)b * 768 + s) * 25 + nt] = reds[tid][0] + reds[tid][1];
    }
}

// ---------------- K4: combine partials -> column max, 1/Z (pad -> 0,0) ----------------
__global__ void k4_combine(const float* __restrict__ pmax, const float* __restrict__ psum,
                           float* __restrict__ colm, float* __restrict__ colzi)
{
    int idx = blockIdx.x * 256 + threadIdx.x;
    if (idx >= 64 * 768) return;
    int s = idx % 768;
    float m = 0.f, zi = 0.f;
    if (s < 725) {
        const float* pm = pmax + (size_t)idx * 25;
        const float* pz = psum + (size_t)idx * 25;
        m = pm[0];
        for (int i = 1; i < 25; ++i) m = fmaxf(m, pm[i]);
        float z = 0.f;
        for (int i = 0; i < 25; ++i) z += pz[i] * __expf(pm[i] - m);
        zi = 1.f / z;
    }
    colm[idx] = m;
    colzi[idx] = zi;
}

// ---------------- K5: recompute f, normalize, y = P @ phi^T (MFMA flash) ----------------
__global__ __launch_bounds__(256) void k5_attn(
    const ushort* __restrict__ thT, const ushort* __restrict__ phiT,
    const ushort* __restrict__ phiC,
    const float* __restrict__ colm, const float* __restrict__ colzi,
    ushort* __restrict__ y)
{
    int nt = blockIdx.x % NTB, b = blockIdx.x / NTB;
    int n0 = nt * 64;
    __shared__ ushort Plds[64][72];
    __shared__ float sm_m[768], sm_zi[768];
    int t = threadIdx.x, lane = t & 63, w = t >> 6;
    int lr = lane & 15, lg = lane >> 4;

    for (int i = t; i < 768; i += 256) {
        sm_m[i]  = colm[(size_t)b * 768 + i];
        sm_zi[i] = colzi[(size_t)b * 768 + i];
    }

    int nq = (w & 1) * 32, sq = (w >> 1) * 32;
    bf16x8 af[2][4];
    #pragma unroll
    for (int mi = 0; mi < 2; ++mi)
        #pragma unroll
        for (int kc = 0; kc < 4; ++kc)
            af[mi][kc] = *reinterpret_cast<const bf16x8*>(
                &thT[((size_t)b * 1600 + n0 + nq + mi * 16 + lr) * 128 + kc * 32 + lg * 8]);

    f32x4 yacc[8] = {};
    int n2q = w * 16;
    __syncthreads();

    for (int sc = 0; sc < 12; ++sc) {
        int s0 = sc * 64;
        f32x4 fa[2][2] = {};
        #pragma unroll
        for (int kc = 0; kc < 4; ++kc) {
            bf16x8 bb[2];
            #pragma unroll
            for (int ni = 0; ni < 2; ++ni)
                bb[ni] = *reinterpret_cast<const bf16x8*>(
                    &phiT[((size_t)b * 768 + s0 + sq + ni * 16 + lr) * 128 + kc * 32 + lg * 8]);
            #pragma unroll
            for (int mi = 0; mi < 2; ++mi)
                #pragma unroll
                for (int ni = 0; ni < 2; ++ni)
                    fa[mi][ni] = __builtin_amdgcn_mfma_f32_16x16x32_bf16(
                        af[mi][kc], bb[ni], fa[mi][ni], 0, 0, 0);
        }
        __syncthreads();   // prev phase-2 reads of Plds complete
        #pragma unroll
        for (int mi = 0; mi < 2; ++mi)
            #pragma unroll
            for (int ni = 0; ni < 2; ++ni) {
                int scol = sq + ni * 16 + lr;
                float m = sm_m[s0 + scol], zi = sm_zi[s0 + scol];
                #pragma unroll
                for (int r = 0; r < 4; ++r) {
                    float p = __expf(fa[mi][ni][r] - m) * zi;
                    Plds[nq + mi * 16 + lg * 4 + r][scol] = f2bf(p);
                }
            }
        __syncthreads();
        #pragma unroll
        for (int kk = 0; kk < 2; ++kk) {
            bf16x8 ap = *reinterpret_cast<const bf16x8*>(&Plds[n2q + lr][kk * 32 + lg * 8]);
            #pragma unroll
            for (int cf = 0; cf < 8; ++cf) {
                bf16x8 bp = *reinterpret_cast<const bf16x8*>(
                    &phiC[((size_t)b * 128 + cf * 16 + lr) * 768 + s0 + kk * 32 + lg * 8]);
                yacc[cf] = __builtin_amdgcn_mfma_f32_16x16x32_bf16(ap, bp, yacc[cf], 0, 0, 0);
            }
        }
    }
    #pragma unroll
    for (int cf = 0; cf < 8; ++cf)
        #pragma unroll
        for (int r = 0; r < 4; ++r)
            y[((size_t)b * 1600 + n0 + n2q + lg * 4 + r) * 128 + cf * 16 + lr] =
                f2bf(yacc[cf][r]);
}

// ---------------- K6: partial online (m,z) over n for y columns ----------------
__global__ __launch_bounds__(128) void k6_ypart(const ushort* __restrict__ y,
                                                float* __restrict__ pm, float* __restrict__ pz)
{
    int b = blockIdx.x >> 4, ch = blockIdx.x & 15;
    int c = threadIdx.x;
    const ushort* yb = y + ((size_t)b * 1600 + ch * 100) * 128 + c;
    float m = -1e30f, z = 0.f;
    for (int r = 0; r < 100; ++r) {
        float v = bf2f(yb[(size_t)r * 128]);
        float nm = fmaxf(m, v);
        z = z * __expf(m - nm) + __expf(v - nm);
        m = nm;
    }
    pm[((size_t)b * 128 + c) * 16 + ch] = m;
    pz[((size_t)b * 128 + c) * 16 + ch] = z;
}

__global__ void k6b_ycomb(const float* __restrict__ pm, const float* __restrict__ pz,
                          float* __restrict__ ym, float* __restrict__ yzi)
{
    int idx = blockIdx.x * 256 + threadIdx.x;
    if (idx >= 64 * 128) return;
    const float* m16 = pm + (size_t)idx * 16;
    const float* z16 = pz + (size_t)idx * 16;
    float m = -1e30f;
    for (int i = 0; i < 16; ++i) m = fmaxf(m, m16[i]);
    float z = 0.f;
    for (int i = 0; i < 16; ++i) z += z16[i] * __expf(m16[i] - m);
    ym[idx] = m;
    yzi[idx] = 1.f / z;
}

// ---------------- K7: softmax(y) -> conv W (MFMA) + residual + BN + ReLU ----------------
__global__ __launch_bounds__(256) void k7_final(
    const ushort* __restrict__ y, const float* __restrict__ ym, const float* __restrict__ yzi,
    const float* __restrict__ Ww, const float* __restrict__ Wb,
    const float* __restrict__ x,
    const float* __restrict__ gamma, const float* __restrict__ beta,
    const float* __restrict__ mean, const float* __restrict__ var,
    float* __restrict__ out)
{
    int nt = blockIdx.x % NTB, b = blockIdx.x / NTB;
    int n0 = nt * 64;
    __shared__ ushort yl[64][136];
    __shared__ float scl[256], shl[256], wbl[256], ml[128], zl[128];
    int t = threadIdx.x, lane = t & 63, w = t >> 6;
    {
        float sc = gamma[t] * rsqrtf(var[t] + 1e-5f);
        scl[t] = sc;
        shl[t] = beta[t] - mean[t] * sc;
        wbl[t] = Wb[t];
        if (t < 128) {
            ml[t] = ym[(size_t)b * 128 + t];
            zl[t] = yzi[(size_t)b * 128 + t];
        }
    }
    __syncthreads();
    int c8 = (t & 15) * 8, rr = t >> 4;
    #pragma unroll
    for (int p = 0; p < 4; ++p) {
        int r = rr + 16 * p;
        bf16x8 v = *reinterpret_cast<const bf16x8*>(
            &y[((size_t)b * 1600 + n0 + r) * 128 + c8]);
        bf16x8 pk;
        #pragma unroll
        for (int j = 0; j < 8; ++j) {
            float f = bf2f((ushort)v[j]);
            pk[j] = (short)f2bf(__expf(f - ml[c8 + j]) * zl[c8 + j]);
        }
        *reinterpret_cast<bf16x8*>(&yl[r][c8]) = pk;
    }
    __syncthreads();
    int lr = lane & 15, lg = lane >> 4;
    int o0 = w * 64;
    f32x4 acc[4][4] = {};
    #pragma unroll
    for (int kc = 0; kc < 4; ++kc) {
        bf16x8 af[4];
        #pragma unroll
        for (int mi = 0; mi < 4; ++mi) {
            const float* wp = &Ww[(size_t)(o0 + mi * 16 + lr) * 128 + kc * 32 + lg * 8];
            float4 w0 = *reinterpret_cast<const float4*>(wp);
            float4 w1 = *reinterpret_cast<const float4*>(wp + 4);
            bf16x8 a;
            a[0] = (short)f2bf(w0.x); a[1] = (short)f2bf(w0.y);
            a[2] = (short)f2bf(w0.z); a[3] = (short)f2bf(w0.w);
            a[4] = (short)f2bf(w1.x); a[5] = (short)f2bf(w1.y);
            a[6] = (short)f2bf(w1.z); a[7] = (short)f2bf(w1.w);
            af[mi] = a;
        }
        #pragma unroll
        for (int ni = 0; ni < 4; ++ni) {
            bf16x8 bfrag = *reinterpret_cast<const bf16x8*>(&yl[ni * 16 + lr][kc * 32 + lg * 8]);
            #pragma unroll
            for (int mi = 0; mi < 4; ++mi)
                acc[mi][ni] = __builtin_amdgcn_mfma_f32_16x16x32_bf16(
                    af[mi], bfrag, acc[mi][ni], 0, 0, 0);
        }
    }
    #pragma unroll
    for (int mi = 0; mi < 4; ++mi)
        #pragma unroll
        for (int ni = 0; ni < 4; ++ni) {
            int n = n0 + ni * 16 + lr;
            #pragma unroll
            for (int r = 0; r < 4; ++r) {
                int o = o0 + mi * 16 + lg * 4 + r;
                size_t off = ((size_t)b * 256 + o) * 1600 + n;
                float v = (acc[mi][ni][r] + wbl[o] + x[off]) * scl[o] + shl[o];
                out[off] = fmaxf(v, 0.f);
            }
        }
}

extern "C" void kernel_launch(void* const* d_in, const int* in_sizes, int n_in,
                              void* d_out, int out_size, void* d_ws, size_t ws_size,
                              hipStream_t stream)
{
    const float* x   = (const float*)d_in[0];
    const float* gw  = (const float*)d_in[1];
    const float* gb  = (const float*)d_in[2];
    const float* tw  = (const float*)d_in[3];
    const float* tb  = (const float*)d_in[4];
    const float* Ww  = (const float*)d_in[5];
    const float* Wb  = (const float*)d_in[6];
    const float* bng = (const float*)d_in[7];
    const float* bnb = (const float*)d_in[8];
    const float* bnm = (const float*)d_in[9];
    const float* bnv = (const float*)d_in[10];
    float* out = (float*)d_out;

    char* base = (char*)d_ws;
    ushort* thT  = (ushort*)(base);               // 26,214,400 B
    ushort* gout = (ushort*)(base + 26214400);    // 26,214,400 B (reused as y)
    ushort* phiC = (ushort*)(base + 52428800);    // 12,582,912 B
    ushort* phiT = (ushort*)(base + 65011712);    // 12,582,912 B
    float* pmax  = (float*)(base + 77594624);     // 4,915,200 B
    float* psum  = (float*)(base + 82509824);     // 4,915,200 B
    float* colm  = (float*)(base + 87425024);     // 196,608 B
    float* colzi = (float*)(base + 87621632);     // 196,608 B
    float* ypm   = (float*)(base + 87818240);     // 524,288 B
    float* ypz   = (float*)(base + 88342528);     // 524,288 B
    float* ymv   = (float*)(base + 88866816);     // 32,768 B
    float* yzi   = (float*)(base + 88899584);     // 32,768 B
    ushort* yv   = gout;                          // alias: gout dead after k2a

    k1_conv<<<64 * NTB, 256, 0, stream>>>(x, gw, gb, tw, tb, gout, thT);
    k2a_psp<<<(64 * 128 * 768) / 256, 256, 0, stream>>>(gout, phiC, phiT);
    k3_stats<<<64 * 25 * 12, 256, 0, stream>>>(thT, phiT, pmax, psum);
    k4_combine<<<(64 * 768) / 256, 256, 0, stream>>>(pmax, psum, colm, colzi);
    k5_attn<<<64 * NTB, 256, 0, stream>>>(thT, phiT, phiC, colm, colzi, yv);
    k6_ypart<<<64 * 16, 128, 0, stream>>>(yv, ypm, ypz);
    k6b_ycomb<<<(64 * 128 + 255) / 256, 256, 0, stream>>>(ypm, ypz, ymv, yzi);
    k7_final<<<64 * NTB, 256, 0, stream>>>(yv, ymv, yzi, Ww, Wb, x, bng, bnb, bnm, bnv, out);
}

// Round 4
// 658.720 us; speedup vs baseline: 1.9277x; 1.0326x over previous
//
#include <hip/hip_runtime.h>

#define NTB 25

typedef float f32x4 __attribute__((ext_vector_type(4)));
typedef short bf16x8 __attribute__((ext_vector_type(8)));

__device__ __forceinline__ ushort f2bf(float f) {
    union { float f; uint u; } v; v.f = f;
    uint u = v.u;
    return (ushort)((u + 0x7fffu + ((u >> 16) & 1u)) >> 16);
}
__device__ __forceinline__ float bf2f(ushort h) {
    union { uint u; float f; } v; v.u = ((uint)h) << 16;
    return v.f;
}

// ---------------- K0: W (256x128) f32 -> bf16 once ----------------
__global__ __launch_bounds__(256) void k0_wconv(const float* __restrict__ Ww,
                                                ushort* __restrict__ Wbf)
{
    int idx = blockIdx.x * 256 + threadIdx.x;
    if (idx < 256 * 128) Wbf[idx] = f2bf(Ww[idx]);
}

// ---------------- K1: fused conv1x1 (g & theta) via MFMA ----------------
__global__ __launch_bounds__(256) void k1_conv(
    const float* __restrict__ x,
    const float* __restrict__ gw, const float* __restrict__ gb,
    const float* __restrict__ tw, const float* __restrict__ tb,
    ushort* __restrict__ gout, ushort* __restrict__ thT)
{
    int nt = blockIdx.x % NTB, b = blockIdx.x / NTB;
    int n0 = nt * 64;
    __shared__ ushort xl[8][64][40];
    int tid = threadIdx.x, lane = tid & 63, w = tid >> 6;

    const float* xb = x + (size_t)b * 256 * 1600;
    int nr = tid & 15, cr = tid >> 4;
    for (int q = 0; q < 16; ++q) {
        int kc = q >> 1, p = q & 1;
        int c = cr + 16 * p;
        float4 v = *reinterpret_cast<const float4*>(
            &xb[(size_t)(kc * 32 + c) * 1600 + n0 + nr * 4]);
        float vv[4] = {v.x, v.y, v.z, v.w};
        #pragma unroll
        for (int j = 0; j < 4; ++j) {
            int n = nr * 4 + j;
            int blk = (c >> 3) ^ ((n >> 2) & 3);
            xl[kc][n][blk * 8 + (c & 7)] = f2bf(vv[j]);
        }
    }
    __syncthreads();

    const float* W    = (w < 2) ? gw : tw;
    const float* bias = (w < 2) ? gb : tb;
    int mrow0 = (w & 1) * 64;
    int lr = lane & 15, lg = lane >> 4;
    f32x4 acc[4][4] = {};

    #pragma unroll
    for (int kc = 0; kc < 8; ++kc) {
        bf16x8 af[4];
        #pragma unroll
        for (int mi = 0; mi < 4; ++mi) {
            const float* wp = &W[(size_t)(mrow0 + mi * 16 + lr) * 256 + kc * 32 + lg * 8];
            float4 w0 = *reinterpret_cast<const float4*>(wp);
            float4 w1 = *reinterpret_cast<const float4*>(wp + 4);
            bf16x8 a;
            a[0] = (short)f2bf(w0.x); a[1] = (short)f2bf(w0.y);
            a[2] = (short)f2bf(w0.z); a[3] = (short)f2bf(w0.w);
            a[4] = (short)f2bf(w1.x); a[5] = (short)f2bf(w1.y);
            a[6] = (short)f2bf(w1.z); a[7] = (short)f2bf(w1.w);
            af[mi] = a;
        }
        #pragma unroll
        for (int ni = 0; ni < 4; ++ni) {
            int n = ni * 16 + lr;
            int blk = lg ^ ((n >> 2) & 3);
            bf16x8 bfrag = *reinterpret_cast<const bf16x8*>(&xl[kc][n][blk * 8]);
            #pragma unroll
            for (int mi = 0; mi < 4; ++mi)
                acc[mi][ni] = __builtin_amdgcn_mfma_f32_16x16x32_bf16(
                    af[mi], bfrag, acc[mi][ni], 0, 0, 0);
        }
    }

    #pragma unroll
    for (int mi = 0; mi < 4; ++mi) {
        float4 bv = *reinterpret_cast<const float4*>(&bias[mrow0 + mi * 16 + lg * 4]);
        float bvv[4] = {bv.x, bv.y, bv.z, bv.w};
        #pragma unroll
        for (int ni = 0; ni < 4; ++ni) {
            int n = n0 + ni * 16 + lr;
            int m = mrow0 + mi * 16 + lg * 4;
            if (w < 2) {
                #pragma unroll
                for (int r = 0; r < 4; ++r)
                    gout[((size_t)b * 128 + m + r) * 1600 + n] = f2bf(acc[mi][ni][r] + bvv[r]);
            } else {
                ushort4 pk;
                pk.x = f2bf(acc[mi][ni][0] + bvv[0]);
                pk.y = f2bf(acc[mi][ni][1] + bvv[1]);
                pk.z = f2bf(acc[mi][ni][2] + bvv[2]);
                pk.w = f2bf(acc[mi][ni][3] + bvv[3]);
                *reinterpret_cast<ushort4*>(&thT[((size_t)b * 1600 + n) * 128 + m]) = pk;
            }
        }
    }
}

// ---------------- K2: PSP pooling (faithful raw reshape), both phi layouts ----------------
__global__ __launch_bounds__(256) void k2a_psp(const ushort* __restrict__ g,
                                               ushort* __restrict__ phiC,
                                               ushort* __restrict__ phiT)
{
    int idx = blockIdx.x * 256 + threadIdx.x;
    if (idx >= 64 * 128 * 768) return;
    int j = idx % 768;
    int bc = idx / 768;
    float outv = 0.f;
    if (j < 725) {
        int ls, off;
        if (j < 25)       { ls = 0; off = 0; }
        else if (j < 125) { ls = 2; off = 25; }
        else if (j < 325) { ls = 3; off = 125; }
        else              { ls = 4; off = 325; }
        int m = j - off;
        int flat = (bc << ls) * 25 + m;
        int a   = flat >> (7 + ls);
        int rem = flat & ((128 << ls) - 1);
        int c2  = rem >> ls;
        int k   = rem & ((1 << ls) - 1);
        int L   = 64 >> ls;
        const ushort* p = g + ((size_t)a << 13) + (c2 << 6) + k * L;
        float sum = 0.f;
        for (int q = 0; q < L; ++q) sum += bf2f(p[q]);
        outv = sum * (1.f / L);
    }
    ushort hv = f2bf(outv);
    phiC[idx] = hv;
    int b = bc >> 7, c = bc & 127;
    phiT[((size_t)b * 768 + j) * 128 + c] = hv;
}

// ---------------- K3: E = exp(theta^T phi) (bf16) + column-sum partials ----------------
// Processes batches [b0, b0+HB); E is indexed by LOCAL batch (fits d_out scratch).
__global__ __launch_bounds__(256) void k3_expf(
    const ushort* __restrict__ thT, const ushort* __restrict__ phiT,
    ushort* __restrict__ E, float* __restrict__ psum, int b0)
{
    int blk = blockIdx.x;
    int st = blk % 12; blk /= 12;
    int nt = blk % 25; int bl = blk / 25;
    int b = b0 + bl;
    int n0 = nt * 64, s0 = st * 64;
    int tid = threadIdx.x, lane = tid & 63, w = tid >> 6;
    int lr = lane & 15, lg = lane >> 4;
    int nrow = n0 + w * 16;

    __shared__ float red[64][4];

    f32x4 acc[4] = {};
    #pragma unroll
    for (int kc = 0; kc < 4; ++kc) {
        bf16x8 a = *reinterpret_cast<const bf16x8*>(
            &thT[((size_t)b * 1600 + nrow + lr) * 128 + kc * 32 + lg * 8]);
        #pragma unroll
        for (int ni = 0; ni < 4; ++ni) {
            bf16x8 bb = *reinterpret_cast<const bf16x8*>(
                &phiT[((size_t)b * 768 + s0 + ni * 16 + lr) * 128 + kc * 32 + lg * 8]);
            acc[ni] = __builtin_amdgcn_mfma_f32_16x16x32_bf16(a, bb, acc[ni], 0, 0, 0);
        }
    }

    #pragma unroll
    for (int ni = 0; ni < 4; ++ni) {
        float se = 0.f;
        float ex[4];
        #pragma unroll
        for (int r = 0; r < 4; ++r) { ex[r] = __expf(acc[ni][r]); se += ex[r]; }
        #pragma unroll
        for (int r = 0; r < 4; ++r)
            E[((size_t)bl * 1600 + nrow + lg * 4 + r) * 768 + s0 + ni * 16 + lr] = f2bf(ex[r]);
        se += __shfl_xor(se, 16);
        se += __shfl_xor(se, 32);
        if (lg == 0) red[ni * 16 + lr][w] = se;
    }
    __syncthreads();
    if (tid < 64) {
        float z = red[tid][0] + red[tid][1] + red[tid][2] + red[tid][3];
        psum[((size_t)b * 768 + s0 + tid) * 25 + nt] = z;
    }
}

// ---------------- K4: Z combine + phiZ[c][s] = phi[c][s]/Z[s] ----------------
__global__ __launch_bounds__(256) void k4_phiz(const float* __restrict__ psum,
                                               const ushort* __restrict__ phiC,
                                               ushort* __restrict__ phiZ)
{
    int idx = blockIdx.x * 256 + threadIdx.x;
    if (idx >= 64 * 768) return;
    int s = idx % 768, b = idx / 768;
    const float* p = psum + (size_t)idx * 25;
    float z = 0.f;
    #pragma unroll
    for (int i = 0; i < 25; ++i) z += p[i];
    float zi = (s < 725) ? 1.f / z : 0.f;
    for (int c = 0; c < 128; ++c) {
        size_t off = ((size_t)b * 128 + c) * 768 + s;
        phiZ[off] = f2bf(bf2f(phiC[off]) * zi);
    }
}

// ---------------- K5: y = E @ phiZ^T (barrier-free GEMM) + col-sum partials of exp(y) ----------------
__global__ __launch_bounds__(256) void k5_pv(
    const ushort* __restrict__ E, const ushort* __restrict__ phiZ,
    ushort* __restrict__ y, float* __restrict__ ypz, int b0)
{
    int nt = blockIdx.x % NTB, bl = blockIdx.x / NTB;
    int b = b0 + bl;
    int n0 = nt * 64;
    int tid = threadIdx.x, lane = tid & 63, w = tid >> 6;
    int lr = lane & 15, lg = lane >> 4;
    int nrow = n0 + w * 16;
    const ushort* Eb = E + (size_t)bl * 1600 * 768;
    const ushort* Pb = phiZ + (size_t)b * 128 * 768;

    __shared__ float yred[4][128];

    f32x4 acc[8] = {};
    #pragma unroll 4
    for (int kc = 0; kc < 24; ++kc) {
        bf16x8 a = *reinterpret_cast<const bf16x8*>(
            &Eb[(size_t)(nrow + lr) * 768 + kc * 32 + lg * 8]);
        #pragma unroll
        for (int cf = 0; cf < 8; ++cf) {
            bf16x8 bb = *reinterpret_cast<const bf16x8*>(
                &Pb[(size_t)(cf * 16 + lr) * 768 + kc * 32 + lg * 8]);
            acc[cf] = __builtin_amdgcn_mfma_f32_16x16x32_bf16(a, bb, acc[cf], 0, 0, 0);
        }
    }

    #pragma unroll
    for (int cf = 0; cf < 8; ++cf) {
        float se = 0.f;
        #pragma unroll
        for (int r = 0; r < 4; ++r) {
            ushort hv = f2bf(acc[cf][r]);
            y[((size_t)b * 1600 + nrow + lg * 4 + r) * 128 + cf * 16 + lr] = hv;
            se += __expf(bf2f(hv));
        }
        se += __shfl_xor(se, 16);
        se += __shfl_xor(se, 32);
        if (lane < 16) yred[w][cf * 16 + lane] = se;
    }
    __syncthreads();
    if (tid < 128) {
        float p = yred[0][tid] + yred[1][tid] + yred[2][tid] + yred[3][tid];
        ypz[((size_t)b * 128 + tid) * 25 + nt] = p;
    }
}

// ---------------- K6b: combine 25 partials -> 1/Z2 per (b,c) ----------------
__global__ void k6b_ycomb(const float* __restrict__ ypz, float* __restrict__ yzi)
{
    int idx = blockIdx.x * 256 + threadIdx.x;
    if (idx >= 64 * 128) return;
    const float* p = ypz + (size_t)idx * 25;
    float z = 0.f;
    #pragma unroll
    for (int i = 0; i < 25; ++i) z += p[i];
    yzi[idx] = 1.f / z;
}

// ---------------- K7: softmax(y) -> conv W (MFMA) + residual + BN + ReLU ----------------
__global__ __launch_bounds__(256) void k7_final(
    const ushort* __restrict__ y, const float* __restrict__ yzi,
    const ushort* __restrict__ Wbf, const float* __restrict__ Wb,
    const float* __restrict__ x,
    const float* __restrict__ gamma, const float* __restrict__ beta,
    const float* __restrict__ mean, const float* __restrict__ var,
    float* __restrict__ out)
{
    int nt = blockIdx.x % NTB, b = blockIdx.x / NTB;
    int n0 = nt * 64;
    __shared__ ushort yl[64][136];
    __shared__ float scl[256], shl[256], wbl[256], zl[128];
    int t = threadIdx.x, lane = t & 63, w = t >> 6;
    {
        float sc = gamma[t] * rsqrtf(var[t] + 1e-5f);
        scl[t] = sc;
        shl[t] = beta[t] - mean[t] * sc;
        wbl[t] = Wb[t];
        if (t < 128) zl[t] = yzi[(size_t)b * 128 + t];
    }
    __syncthreads();
    int c8 = (t & 15) * 8, rr = t >> 4;
    #pragma unroll
    for (int p = 0; p < 4; ++p) {
        int r = rr + 16 * p;
        bf16x8 v = *reinterpret_cast<const bf16x8*>(
            &y[((size_t)b * 1600 + n0 + r) * 128 + c8]);
        bf16x8 pk;
        #pragma unroll
        for (int j = 0; j < 8; ++j) {
            float f = bf2f((ushort)v[j]);
            pk[j] = (short)f2bf(__expf(f) * zl[c8 + j]);
        }
        *reinterpret_cast<bf16x8*>(&yl[r][c8]) = pk;
    }
    __syncthreads();
    int lr = lane & 15, lg = lane >> 4;
    int o0 = w * 64;
    f32x4 acc[4][4] = {};
    #pragma unroll
    for (int kc = 0; kc < 4; ++kc) {
        bf16x8 af[4];
        #pragma unroll
        for (int mi = 0; mi < 4; ++mi)
            af[mi] = *reinterpret_cast<const bf16x8*>(
                &Wbf[(size_t)(o0 + mi * 16 + lr) * 128 + kc * 32 + lg * 8]);
        #pragma unroll
        for (int ni = 0; ni < 4; ++ni) {
            bf16x8 bfrag = *reinterpret_cast<const bf16x8*>(&yl[ni * 16 + lr][kc * 32 + lg * 8]);
            #pragma unroll
            for (int mi = 0; mi < 4; ++mi)
                acc[mi][ni] = __builtin_amdgcn_mfma_f32_16x16x32_bf16(
                    af[mi], bfrag, acc[mi][ni], 0, 0, 0);
        }
    }
    #pragma unroll
    for (int mi = 0; mi < 4; ++mi)
        #pragma unroll
        for (int ni = 0; ni < 4; ++ni) {
            int n = n0 + ni * 16 + lr;
            #pragma unroll
            for (int r = 0; r < 4; ++r) {
                int o = o0 + mi * 16 + lg * 4 + r;
                size_t off = ((size_t)b * 256 + o) * 1600 + n;
                float v = (acc[mi][ni][r] + wbl[o] + x[off]) * scl[o] + shl[o];
                out[off] = fmaxf(v, 0.f);
            }
        }
}

extern "C" void kernel_launch(void* const* d_in, const int* in_sizes, int n_in,
                              void* d_out, int out_size, void* d_ws, size_t ws_size,
                              hipStream_t stream)
{
    const float* x   = (const float*)d_in[0];
    const float* gw  = (const float*)d_in[1];
    const float* gb  = (const float*)d_in[2];
    const float* tw  = (const float*)d_in[3];
    const float* tb  = (const float*)d_in[4];
    const float* Ww  = (const float*)d_in[5];
    const float* Wb  = (const float*)d_in[6];
    const float* bng = (const float*)d_in[7];
    const float* bnb = (const float*)d_in[8];
    const float* bnm = (const float*)d_in[9];
    const float* bnv = (const float*)d_in[10];
    float* out = (float*)d_out;

    char* base = (char*)d_ws;
    ushort* thT  = (ushort*)(base);               // 26,214,400 B
    ushort* gout = (ushort*)(base + 26214400);    // 26,214,400 B (reused as y)
    ushort* phiC = (ushort*)(base + 52428800);    // 12,582,912 B
    ushort* phiT = (ushort*)(base + 65011712);    // 12,582,912 B
    float* psum  = (float*)(base + 77594624);     //  4,915,200 B
    ushort* phiZ = (ushort*)(base + 82509824);    // 12,582,912 B
    float* ypz   = (float*)(base + 95092736);     //    819,200 B
    float* yzi   = (float*)(base + 95911936);     //     32,768 B
    ushort* Wbf  = (ushort*)(base + 95944704);    //     65,536 B
    ushort* yv   = gout;                          // alias: gout dead after k2a
    // E scratch lives in the d_out region: per half-batch 32*1600*768*2 B
    // = 78,643,200 B <= out bytes (104,857,600 B). k7 rewrites all of out last.
    ushort* E    = (ushort*)d_out;

    k0_wconv<<<128, 256, 0, stream>>>(Ww, Wbf);
    k1_conv<<<64 * NTB, 256, 0, stream>>>(x, gw, gb, tw, tb, gout, thT);
    k2a_psp<<<(64 * 128 * 768) / 256, 256, 0, stream>>>(gout, phiC, phiT);

    // half 0: batches 0..31
    k3_expf<<<32 * 25 * 12, 256, 0, stream>>>(thT, phiT, E, psum, 0);
    // k4 needs ALL psum partials for its batches; psum for b in [0,32) complete here.
    // But k4 covers all 64 batches; split it per half to keep ordering simple.
    k4_phiz<<<(32 * 768) / 256, 256, 0, stream>>>(psum, phiC, phiZ);
    k5_pv<<<32 * NTB, 256, 0, stream>>>(E, phiZ, yv, ypz, 0);

    // half 1: batches 32..63
    k3_expf<<<32 * 25 * 12, 256, 0, stream>>>(thT, phiT, E, psum, 32);
    k4_phiz<<<(32 * 768) / 256, 256, 0, stream>>>(psum + (size_t)32 * 768 * 25,
                                                  phiC + (size_t)32 * 128 * 768,
                                                  phiZ + (size_t)32 * 128 * 768);
    k5_pv<<<32 * NTB, 256, 0, stream>>>(E, phiZ, yv, ypz, 32);

    k6b_ycomb<<<32, 256, 0, stream>>>(ypz, yzi);
    k7_final<<<64 * NTB, 256, 0, stream>>>(yv, yzi, Wbf, Wb, x, bng, bnb, bnm, bnv, out);
}